// Round 3
// baseline (119.818 us; speedup 1.0000x reference)
//
#include <hip/hip_runtime.h>

// Valid 3x3 cross-correlation + scalar bias.
// x: [8192][8192] f32 -> out: [8190][8190] f32.
// Memory-bound. Ideal traffic ~410-440 MB (L3 absorbs part of the input
// re-read across replays) -> ~65-70 us at ~6.3 TB/s.
//
// Round 2: 93 us, 4.7 TB/s. Fixes this round:
//  - drop non-temporal stores (they inflated WRITE 268->296 MB, no FETCH win)
//  - alignment-aware stores: out row stride 8190*4 B == 8 mod 16, so odd
//    output rows are only 8B-aligned. r base is a multiple of 4 => parity of
//    (r+i) == parity of i (compile-time): even i -> 2x dwordx4, odd i -> 4x
//    dwordx2. No line-split stores.
//  - cols 8..9 loaded as one aligned float2.

static constexpr int H  = 8192;
static constexpr int W  = 8192;
static constexpr int OH = H - 2;   // 8190
static constexpr int OW = W - 2;   // 8190

typedef float f32x4 __attribute__((ext_vector_type(4)));
typedef float f32x2 __attribute__((ext_vector_type(2)));

// blockDim = (64, 4): 512 cols x 16 rows per block.
// gridDim  = (16, 512).
__global__ __launch_bounds__(256) void conv3x3_kernel(
    const float* __restrict__ x,
    const float* __restrict__ w,
    const float* __restrict__ bias,
    float* __restrict__ out)
{
    const int c = (blockIdx.x * 64 + (int)threadIdx.x) * 8;  // output col base
    const int r = (blockIdx.y * 4 + (int)threadIdx.y) * 4;   // output row base (mult of 4)
    if (r >= OH || c >= OW) return;

    float wk[3][3];
    #pragma unroll
    for (int i = 0; i < 3; ++i)
        #pragma unroll
        for (int j = 0; j < 3; ++j)
            wk[i][j] = w[i * 3 + j];
    const float b = bias[0];

    // Only the last col-group (c == 8184) lacks cols c+8, c+9; those inputs
    // only feed outputs j=6,7 which are OOB there anyway.
    const bool colFast = (c + 10 <= W);

    // Load 6 input rows x 10 cols up-front (24 independent loads in flight).
    // x rows are 16B-aligned at col c (8192*4 % 16 == 0, c % 8 == 0).
    float in[6][10];
    #pragma unroll
    for (int t = 0; t < 6; ++t) {
        int rr = r + t; rr = (rr < H) ? rr : (H - 1);
        const float* row = x + (size_t)rr * W + c;
        const f32x4 va = *reinterpret_cast<const f32x4*>(row);
        const f32x4 vb = *reinterpret_cast<const f32x4*>(row + 4);
        in[t][0] = va.x; in[t][1] = va.y; in[t][2] = va.z; in[t][3] = va.w;
        in[t][4] = vb.x; in[t][5] = vb.y; in[t][6] = vb.z; in[t][7] = vb.w;
        if (colFast) {
            const f32x2 vc = *reinterpret_cast<const f32x2*>(row + 8);
            in[t][8] = vc.x; in[t][9] = vc.y;
        } else {
            in[t][8] = 0.0f; in[t][9] = 0.0f;
        }
    }

    float acc[4][8];
    #pragma unroll
    for (int i = 0; i < 4; ++i)
        #pragma unroll
        for (int j = 0; j < 8; ++j)
            acc[i][j] = b;

    #pragma unroll
    for (int i = 0; i < 4; ++i) {
        #pragma unroll
        for (int kr = 0; kr < 3; ++kr) {
            const int t = i + kr;
            const float k0 = wk[kr][0], k1 = wk[kr][1], k2 = wk[kr][2];
            #pragma unroll
            for (int j = 0; j < 8; ++j)
                acc[i][j] = fmaf(k0, in[t][j],
                            fmaf(k1, in[t][j + 1],
                            fmaf(k2, in[t][j + 2], acc[i][j])));
        }
    }

    #pragma unroll
    for (int i = 0; i < 4; ++i) {
        if (r + i < OH) {
            float* orow = out + (size_t)(r + i) * OW + c;
            if (c + 8 <= OW) {
                if ((i & 1) == 0) {
                    // even output row: 16B-aligned
                    f32x4 o0 = { acc[i][0], acc[i][1], acc[i][2], acc[i][3] };
                    f32x4 o1 = { acc[i][4], acc[i][5], acc[i][6], acc[i][7] };
                    *reinterpret_cast<f32x4*>(orow)     = o0;
                    *reinterpret_cast<f32x4*>(orow + 4) = o1;
                } else {
                    // odd output row: only 8B-aligned -> dwordx2 stores
                    f32x2 o0 = { acc[i][0], acc[i][1] };
                    f32x2 o1 = { acc[i][2], acc[i][3] };
                    f32x2 o2 = { acc[i][4], acc[i][5] };
                    f32x2 o3 = { acc[i][6], acc[i][7] };
                    *reinterpret_cast<f32x2*>(orow)     = o0;
                    *reinterpret_cast<f32x2*>(orow + 2) = o1;
                    *reinterpret_cast<f32x2*>(orow + 4) = o2;
                    *reinterpret_cast<f32x2*>(orow + 6) = o3;
                }
            } else {
                // c == 8184: outputs j=0..5 valid (c+5 == 8189 == OW-1).
                #pragma unroll
                for (int j = 0; j < 6; ++j)
                    orow[j] = acc[i][j];
            }
        }
    }
}

extern "C" void kernel_launch(void* const* d_in, const int* in_sizes, int n_in,
                              void* d_out, int out_size, void* d_ws, size_t ws_size,
                              hipStream_t stream) {
    const float* x    = (const float*)d_in[0];
    const float* w    = (const float*)d_in[1];
    const float* bias = (const float*)d_in[2];
    float* out        = (float*)d_out;

    dim3 block(64, 4, 1);
    dim3 grid((OW + 512 - 1) / 512,    // 16
              (OH + 16 - 1) / 16,      // 512
              1);
    conv3x3_kernel<<<grid, block, 0, stream>>>(x, w, bias, out);
}

// Round 4
// 93.178 us; speedup vs baseline: 1.2859x; 1.2859x over previous
//
#include <hip/hip_runtime.h>

// Valid 3x3 cross-correlation + scalar bias.
// x: [8192][8192] f32 -> out: [8190][8190] f32.
// Memory-bound. Ideal steady-state traffic ~410 MB -> ~65 us @ 6.3 TB/s.
//
// History:
//  R1: 212 us — latency-bound (VGPR=16).
//  R2: 93 us — 4x8 per-thread tile, NT dwordx4 stores (odd rows misaligned,
//      WRITE 296 MB).
//  R3: 120 us — dropped NT + parity-split stores: REGRESSION. Steady-state
//      replays lost input L3 residency to output write allocation.
//  R4 (this): NT stores restored AND parity-aligned widths:
//      even output rows (16B-aligned): 2x NT dwordx4
//      odd  output rows (8B-aligned):  4x NT dwordx2
//      -> no partial-line NT writes, output bypasses cache, input stays in L3.

static constexpr int H  = 8192;
static constexpr int W  = 8192;
static constexpr int OH = H - 2;   // 8190
static constexpr int OW = W - 2;   // 8190

typedef float f32x4 __attribute__((ext_vector_type(4)));
typedef float f32x2 __attribute__((ext_vector_type(2)));

// blockDim = (64, 4): 512 cols x 16 rows per block.
// gridDim  = (16, 512).
__global__ __launch_bounds__(256) void conv3x3_kernel(
    const float* __restrict__ x,
    const float* __restrict__ w,
    const float* __restrict__ bias,
    float* __restrict__ out)
{
    const int c = (blockIdx.x * 64 + (int)threadIdx.x) * 8;  // output col base
    const int r = (blockIdx.y * 4 + (int)threadIdx.y) * 4;   // output row base (mult of 4)
    if (r >= OH || c >= OW) return;

    float wk[3][3];
    #pragma unroll
    for (int i = 0; i < 3; ++i)
        #pragma unroll
        for (int j = 0; j < 3; ++j)
            wk[i][j] = w[i * 3 + j];
    const float b = bias[0];

    // Only the last col-group (c == 8184) lacks cols c+8, c+9; those inputs
    // only feed outputs j=6,7 which are OOB there anyway.
    const bool colFast = (c + 10 <= W);

    // Load 6 input rows x 10 cols up-front (18 independent loads in flight).
    // x rows are 16B-aligned at col c (8192*4 % 16 == 0, c % 8 == 0).
    float in[6][10];
    #pragma unroll
    for (int t = 0; t < 6; ++t) {
        int rr = r + t; rr = (rr < H) ? rr : (H - 1);
        const float* row = x + (size_t)rr * W + c;
        const f32x4 va = *reinterpret_cast<const f32x4*>(row);
        const f32x4 vb = *reinterpret_cast<const f32x4*>(row + 4);
        in[t][0] = va.x; in[t][1] = va.y; in[t][2] = va.z; in[t][3] = va.w;
        in[t][4] = vb.x; in[t][5] = vb.y; in[t][6] = vb.z; in[t][7] = vb.w;
        if (colFast) {
            const f32x2 vc = *reinterpret_cast<const f32x2*>(row + 8);
            in[t][8] = vc.x; in[t][9] = vc.y;
        } else {
            in[t][8] = 0.0f; in[t][9] = 0.0f;
        }
    }

    float acc[4][8];
    #pragma unroll
    for (int i = 0; i < 4; ++i)
        #pragma unroll
        for (int j = 0; j < 8; ++j)
            acc[i][j] = b;

    #pragma unroll
    for (int i = 0; i < 4; ++i) {
        #pragma unroll
        for (int kr = 0; kr < 3; ++kr) {
            const int t = i + kr;
            const float k0 = wk[kr][0], k1 = wk[kr][1], k2 = wk[kr][2];
            #pragma unroll
            for (int j = 0; j < 8; ++j)
                acc[i][j] = fmaf(k0, in[t][j],
                            fmaf(k1, in[t][j + 1],
                            fmaf(k2, in[t][j + 2], acc[i][j])));
        }
    }

    #pragma unroll
    for (int i = 0; i < 4; ++i) {
        if (r + i < OH) {
            float* orow = out + (size_t)(r + i) * OW + c;
            if (c + 8 <= OW) {
                if ((i & 1) == 0) {
                    // even output row: 16B-aligned -> NT dwordx4
                    f32x4 o0 = { acc[i][0], acc[i][1], acc[i][2], acc[i][3] };
                    f32x4 o1 = { acc[i][4], acc[i][5], acc[i][6], acc[i][7] };
                    __builtin_nontemporal_store(o0, reinterpret_cast<f32x4*>(orow));
                    __builtin_nontemporal_store(o1, reinterpret_cast<f32x4*>(orow + 4));
                } else {
                    // odd output row: 8B-aligned -> NT dwordx2 (no line splits)
                    f32x2 o0 = { acc[i][0], acc[i][1] };
                    f32x2 o1 = { acc[i][2], acc[i][3] };
                    f32x2 o2 = { acc[i][4], acc[i][5] };
                    f32x2 o3 = { acc[i][6], acc[i][7] };
                    __builtin_nontemporal_store(o0, reinterpret_cast<f32x2*>(orow));
                    __builtin_nontemporal_store(o1, reinterpret_cast<f32x2*>(orow + 2));
                    __builtin_nontemporal_store(o2, reinterpret_cast<f32x2*>(orow + 4));
                    __builtin_nontemporal_store(o3, reinterpret_cast<f32x2*>(orow + 6));
                }
            } else {
                // c == 8184: outputs j=0..5 valid (c+5 == 8189 == OW-1).
                #pragma unroll
                for (int j = 0; j < 6; ++j)
                    __builtin_nontemporal_store(acc[i][j], orow + j);
            }
        }
    }
}

extern "C" void kernel_launch(void* const* d_in, const int* in_sizes, int n_in,
                              void* d_out, int out_size, void* d_ws, size_t ws_size,
                              hipStream_t stream) {
    const float* x    = (const float*)d_in[0];
    const float* w    = (const float*)d_in[1];
    const float* bias = (const float*)d_in[2];
    float* out        = (float*)d_out;

    dim3 block(64, 4, 1);
    dim3 grid((OW + 512 - 1) / 512,    // 16
              (OH + 16 - 1) / 16,      // 512
              1);
    conv3x3_kernel<<<grid, block, 0, stream>>>(x, w, bias, out);
}